// Round 5
// baseline (45.782 us; speedup 1.0000x reference)
//
#include <hip/hip_runtime.h>

typedef unsigned short u16;
typedef __attribute__((ext_vector_type(4))) unsigned short u16x4;
typedef __attribute__((ext_vector_type(8))) unsigned short u16x8;
typedef __attribute__((ext_vector_type(8))) short bf16x8;
typedef __attribute__((ext_vector_type(4))) float f32x4;

#define QN 512
#define SN 128
#define TN 16
#define DN 512
#define QT (QN*TN)   /* 8192 query frames */
#define STF (SN*TN)  /* 2048 support frames */

#if __has_builtin(__builtin_amdgcn_exp2f)
#define EXP2F __builtin_amdgcn_exp2f
#else
#define EXP2F exp2f
#endif
#if __has_builtin(__builtin_amdgcn_logf)
#define LOG2F __builtin_amdgcn_logf
#else
#define LOG2F log2f
#endif

#define KEXP 2.8853900817779268f   /* 1/(lbda*ln2), lbda=0.5 */
#define CLOG 0.34657359027997264f  /* lbda*ln2 */
#define K2   7.38905609893065f     /* exp(1/lbda) = e^2, per-row rescale */

__device__ __forceinline__ u16 f2bf(float f){
  union { float f; unsigned int u; } v; v.f = f;
  unsigned int u = v.u;
  unsigned int r = (u + 0x7fffu + ((u >> 16) & 1u)) >> 16;
  return (u16)r;
}
__device__ __forceinline__ float bf2f(u16 v){
  union { unsigned int u; float f; } x; x.u = ((unsigned int)v) << 16; return x.f;
}

__device__ __forceinline__ void gld16(const void* g, unsigned lds_addr){
  __builtin_amdgcn_global_load_lds(
      (const __attribute__((address_space(1))) unsigned int*)(unsigned long long)g,
      (__attribute__((address_space(3))) unsigned int*)lds_addr,
      16, 0, 0);
}

// ---------------- prep: f32 -> bf16 convert + row norms ----------------
__global__ __launch_bounds__(256) void prep_kernel(
    const float* __restrict__ sup, const float* __restrict__ tgt,
    u16* __restrict__ Abf, u16* __restrict__ Bbf,
    float* __restrict__ nx, float* __restrict__ ny)
{
  int w = (int)((blockIdx.x * blockDim.x + threadIdx.x) >> 6);
  int lane = threadIdx.x & 63;
  if (w >= QT + STF) return;
  bool isQ = (w < QT);
  int row = isQ ? w : (w - QT);
  const float* src = (isQ ? tgt : sup) + (size_t)row * DN + lane * 8;
  f32x4 x0 = *(const f32x4*)src;
  f32x4 x1 = *(const f32x4*)(src + 4);
  float ss = 0.f;
  #pragma unroll
  for (int i = 0; i < 4; ++i) { ss += x0[i]*x0[i]; ss += x1[i]*x1[i]; }
  u16x8 o;
  #pragma unroll
  for (int i = 0; i < 4; ++i) { o[i] = f2bf(x0[i]); o[i+4] = f2bf(x1[i]); }
  u16* dst = (isQ ? Abf : Bbf) + (size_t)row * DN + lane * 8;
  *(u16x8*)dst = o;
  #pragma unroll
  for (int off = 32; off; off >>= 1) ss += __shfl_xor(ss, off);
  if (lane == 0) (isQ ? nx : ny)[row] = sqrtf(ss);
}

// ---------------- fused: depth-3 gload_lds MFMA GEMM -> LDS ed-tiles -> exp-domain DP ----
// tile 128x128 frames (8q x 8s) -> 64 pairs x 2 dirs = 128 DP tasks x 512B = 64KB dt.
// GEMM: BK=32 quad-buffered A[128][32]+B[128][32] per buf (16KB x 4 = 64KB, union w/ dt),
// global_load_lds width-16 linear dest, pre-swizzled source (granule ^ (row>>1)&3),
// counted vmcnt(8) depth-3 prefetch, ONE s_barrier per iter.
__global__ __launch_bounds__(256, 2) void fused_kernel(
    const u16* __restrict__ Abf, const u16* __restrict__ Bbf,
    const float* __restrict__ nx, const float* __restrict__ ny,
    float* __restrict__ out)
{
  __shared__ __align__(128) char smem[65536];
  const int t = threadIdx.x;
  // XCD-chunked swizzle: 1024 blocks, XCD = bid%8 -> give each XCD 128 consecutive work ids
  const int bid = blockIdx.x;
  const int wsw = (bid & 7) * 128 + (bid >> 3);
  const int bx = wsw & 15, by = wsw >> 4;
  const int m0 = by * 128;   // query-frame base
  const int n0 = bx * 128;   // support-frame base
  const int wave = t >> 6, lane = t & 63;
  const int wr = wave >> 1, wc = wave & 1;
  const int lhi = lane >> 4, llo = lane & 15;

  const unsigned sbase = (unsigned)(unsigned long long)(void*)smem;

  // staging: instr i (i=0,1) covers rows [i*64 + wave*16, +16); lane -> row lane>>2,
  // phys granule lane&3 holds logical granule (lane&3) ^ ((row>>1)&3) = ^((lane>>3)&3).
  const int rsub = lane >> 2;
  const int lg = (lane & 3) ^ ((lane >> 3) & 3);
  const u16* pA[2]; const u16* pB[2];
  unsigned ldsA[2], ldsB[2];
  #pragma unroll
  for (int i = 0; i < 2; ++i) {
    int r = i*64 + wave*16 + rsub;
    pA[i] = Abf + (size_t)(m0 + r) * DN + lg*8;
    pB[i] = Bbf + (size_t)(n0 + r) * DN + lg*8;
    unsigned ro = (unsigned)(i*4096 + wave*1024);
    ldsA[i] = __builtin_amdgcn_readfirstlane(sbase + ro);
    ldsB[i] = __builtin_amdgcn_readfirstlane(sbase + 8192u + ro);
  }

  f32x4 acc[4][4] = {};

  auto STAGE = [&](int sel, int koff) {
    unsigned bo = (unsigned)(sel << 14);
    #pragma unroll
    for (int i = 0; i < 2; ++i) {
      gld16(pA[i] + koff, ldsA[i] + bo);
      gld16(pB[i] + koff, ldsB[i] + bo);
    }
  };

  const int xg = (llo >> 1) & 3;
  const int po = ((0 ^ xg) << 4);  // granule index gets ^ lhi at read
  auto COMPUTE = [&](int sel) {
    char* ba = smem + (sel << 14);
    char* bb = ba + 8192;
    bf16x8 af[4], bfr[4];
    #pragma unroll
    for (int mi = 0; mi < 4; ++mi)
      af[mi] = *(const bf16x8*)(ba + (wr*64 + mi*16 + llo)*64 + (((lhi ^ xg)) << 4));
    #pragma unroll
    for (int ni = 0; ni < 4; ++ni)
      bfr[ni] = *(const bf16x8*)(bb + (wc*64 + ni*16 + llo)*64 + (((lhi ^ xg)) << 4));
    #pragma unroll
    for (int mi = 0; mi < 4; ++mi)
      #pragma unroll
      for (int ni = 0; ni < 4; ++ni)
        acc[mi][ni] = __builtin_amdgcn_mfma_f32_16x16x32_bf16(af[mi], bfr[ni], acc[mi][ni], 0, 0, 0);
  };
  (void)po;

  // prologue: tiles 0,1,2 into bufs 0,1,2
  STAGE(0, 0); STAGE(1, 32); STAGE(2, 64);
  #pragma unroll 1
  for (int it = 0; it < 14; ++it) {
    asm volatile("s_waitcnt vmcnt(8)" ::: "memory");
    __builtin_amdgcn_s_barrier();
    asm volatile("" ::: "memory");
    if (it < 13) STAGE((it + 3) & 3, (it + 3) * 32);
    asm volatile("" ::: "memory");
    COMPUTE(it & 3);
  }
  asm volatile("s_waitcnt vmcnt(4)" ::: "memory");
  __builtin_amdgcn_s_barrier();
  asm volatile("" ::: "memory");
  COMPUTE(2);
  asm volatile("s_waitcnt vmcnt(0)" ::: "memory");
  __builtin_amdgcn_s_barrier();
  asm volatile("" ::: "memory");
  COMPUTE(3);
  __syncthreads();  // GEMM LDS reads done; smem about to be reused as dt

  // ---- epilogue: ed = exp2((acc*rcp(den) - 1)*KEXP), write both orientations ----
  // dt element (l,m) of task T at byte: T*512 + ((l*32 + m*2) ^ ((l&12)<<3) ^ ((T&31)<<4))
  float nxv[4][4];
  #pragma unroll
  for (int mi = 0; mi < 4; ++mi)
    #pragma unroll
    for (int j = 0; j < 4; ++j)
      nxv[mi][j] = nx[m0 + wr*64 + mi*16 + lhi*4 + j];

  #pragma unroll
  for (int ni = 0; ni < 4; ++ni) {
    int gcol = n0 + wc*64 + ni*16 + llo;
    float nyv = ny[gcol];
    int sloc = wc*4 + ni;
    int ts = llo;
    #pragma unroll
    for (int mi = 0; mi < 4; ++mi) {
      int qloc = wr*4 + mi;
      int t0 = (qloc*8 + sloc) * 2;   // dir-0 task
      int t1 = t0 + 1;                // dir-1 task (transposed)
      int swz0 = (t0 & 31) << 4, swz1 = (t1 & 31) << 4;
      u16x4 pk;
      #pragma unroll
      for (int j = 0; j < 4; ++j) {
        int tq = lhi*4 + j;
        float den = nxv[mi][j] * nyv + 0.01f;
        float r = __builtin_amdgcn_rcpf(den);
        float ed = EXP2F(fmaf(acc[mi][ni][j] * r, KEXP, -KEXP));
        u16 e16 = f2bf(ed);
        pk[j] = e16;
        // dir0: element (l=tq, m=ts)
        *(u16*)(smem + t0*512 + ((tq*32 + ts*2) ^ ((tq&12)<<3) ^ swz0)) = e16;
      }
      // dir1: elements (l=ts, m=tq..tq+3), 8B store
      *(u16x4*)(smem + t1*512 + ((ts*32 + lhi*8) ^ ((ts&12)<<3) ^ swz1)) = pk;
    }
  }
  __syncthreads();

  // ---- exp-domain DP, one task per thread (threads 0..127) ----
  // chain form: F[m] = fma(e[m], F[m-1], c[m]) with c[] precomputed from prev row
  if (t < 128) {
    const char* tb = smem + t * 512;
    const int swz = (t & 31) << 4;
    float F[18];
    {
      u16x8 g0 = *(const u16x8*)(tb + (0 ^ swz));
      u16x8 g1 = *(const u16x8*)(tb + (16 ^ swz));
      float c = 1.0f;
      F[0] = 1.0f;
      #pragma unroll
      for (int m = 1; m <= 8; ++m)  { c *= bf2f(g0[m-1]); F[m] = c; }
      #pragma unroll
      for (int m = 9; m <= 16; ++m) { c *= bf2f(g1[m-9]); F[m] = c; }
      F[17] = c;
    }
    // prefetch row 1
    u16x8 h0 = *(const u16x8*)(tb + ((32 ^ ((1&12)<<3)) ^ swz));
    u16x8 h1 = *(const u16x8*)(tb + (((32+16) ^ ((1&12)<<3)) ^ swz));
    float rowc = 1.0f;
    #pragma unroll 1
    for (int l = 1; l < 16; ++l) {
      u16x8 n0v, n1v;
      if (l < 15) {
        int lb = (l+1)*32, lx = ((l+1)&12)<<3;
        n0v = *(const u16x8*)(tb + ((lb ^ lx) ^ swz));
        n1v = *(const u16x8*)(tb + (((lb+16) ^ lx) ^ swz));
      }
      rowc *= K2;
      float e[16];
      #pragma unroll
      for (int m = 0; m < 8; ++m)  e[m]   = bf2f(h0[m]);
      #pragma unroll
      for (int m = 0; m < 8; ++m)  e[m+8] = bf2f(h1[m]);
      // setup (parallel, from OLD F = prev row)
      float c[18];
      c[1] = e[0]*K2*(F[0] + F[1]);            // edge m=1: 3 preds
      #pragma unroll
      for (int m = 2; m <= 16; ++m) c[m] = e[m-1]*K2*F[m-1];
      c[17] = K2*(F[16] + F[17]);              // edge m=17: 3 preds, ed=1
      // serial chain: 1 fma per cell
      F[0] = rowc;
      #pragma unroll
      for (int m = 1; m <= 16; ++m) F[m] = fmaf(e[m-1], F[m-1], c[m]);
      F[17] = F[16] + c[17];
      h0 = n0v; h1 = n1v;
    }
    float res = 15.0f - CLOG * LOG2F(F[17]);
    float other = __shfl_xor(res, 1);
    if (!(t & 1)) {
      int pair = t >> 1, qloc = pair >> 3, sloc = pair & 7;
      out[(size_t)(by*8 + qloc) * SN + bx*8 + sloc] = res + other;
    }
  }
}

// ---------------- launch ----------------
extern "C" void kernel_launch(void* const* d_in, const int* in_sizes, int n_in,
                              void* d_out, int out_size, void* d_ws, size_t ws_size,
                              hipStream_t stream)
{
  const float* sup = (const float*)d_in[0];  // [128,16,512]
  const float* tgt = (const float*)d_in[1];  // [512,16,512]
  float* out = (float*)d_out;                // [512,128]
  char* ws = (char*)d_ws;

  u16* Abf = (u16*)(ws);                     // 8192*512*2  = 8,388,608
  u16* Bbf = (u16*)(ws + 8388608);           // 2048*512*2  = 2,097,152
  float* nx = (float*)(ws + 10485760);       // 8192*4
  float* ny = (float*)(ws + 10518528);       // 2048*4

  prep_kernel<<<dim3((QT + STF) / 4), dim3(256), 0, stream>>>(sup, tgt, Abf, Bbf, nx, ny);
  fused_kernel<<<dim3(1024), dim3(256), 0, stream>>>(Abf, Bbf, nx, ny, out);
}